// Round 9
// baseline (833.647 us; speedup 1.0000x reference)
//
#include <hip/hip_runtime.h>

// GRU seq2seq, MI355X gfx950. Round 9: compile-time parity + cheaper h-round
//   + combine/MFMA overlap ordering.
//   Structure (pinned by HW): 128 blocks x 512 thr, 1 block/CU, 2 waves/SIMD
//   (block weight footprint 308 regs/SIMD of the 512-reg file), wave w owns
//   gate cols [w*16,+16), weights register/AGPR-resident, 1-barrier encoder
//   phase (L0(i)+L1(i-1)), 2-phase decoder. This round: x2-unrolled loops
//   (LDS parity compile-time), h-store via round-half-up (2 VALU), encoder
//   body ordered L0-MFMA / L1-MFMA / L0-combine / L1-combine so combine VALU
//   overlaps in-flight MFMA latency.

typedef unsigned short ushort_t;
typedef unsigned int uint_t;
typedef __attribute__((ext_vector_type(8))) short short8;
typedef __attribute__((ext_vector_type(4))) float f32x4;

#define BT   16
#define NT   512
#define HD   128
#define TIN  336
#define TOUT 168
#define NFE  16
#define NB   128

#define SC_RZ (-1.44269504089f)   // -log2(e)
#define SC_N  (-2.88539008177f)   // -2*log2(e)

#define OFF_EWHH0 0
#define OFF_EWIH1 6144
#define OFF_EWHH1 12288
#define OFF_DWHH0 18432
#define OFF_DWIH1 24576
#define OFF_DWHH1 30720
#define OFF_EWIH0 36864
#define OFF_FW1   38400

__device__ __forceinline__ ushort_t f2bf(float f) {      // RNE (prep only)
    union { float f; uint_t u; } v; v.f = f;
    uint_t r = v.u + 0x7FFFu + ((v.u >> 16) & 1u);
    return (ushort_t)(r >> 16);
}
__device__ __forceinline__ ushort_t f2bf_h(float f) {    // round-half-up, 2 VALU
    union { float f; uint_t u; } v; v.f = f;
    return (ushort_t)((v.u + 0x8000u) >> 16);
}
__device__ __forceinline__ f32x4 splat4(float v) {
    return (f32x4){v, v, v, v};
}
__device__ __forceinline__ float sig2(float t) {         // sigmoid of pre-scaled acc
    return __builtin_amdgcn_rcpf(1.f + __builtin_amdgcn_exp2f(t));
}
__device__ __forceinline__ void barrier_lds() {
    asm volatile("s_waitcnt lgkmcnt(0)\n\ts_barrier" ::: "memory");
}

// ---------------- prep: fp32 weights -> bf16 MFMA B-fragments ----------------
// Gate matrices PRE-SCALED: rows [0,256) by -log2e, rows [256,384) by -2log2e.
extern "C" __global__ __launch_bounds__(64)
void prep_kernel(const float* __restrict__ eWhh0, const float* __restrict__ eWih1,
                 const float* __restrict__ eWhh1, const float* __restrict__ dWhh0,
                 const float* __restrict__ dWih1, const float* __restrict__ dWhh1,
                 const float* __restrict__ eWih0, const float* __restrict__ fW1,
                 uint4* __restrict__ ws)
{
    const int g = blockIdx.x;
    const int L = threadIdx.x;
    const int n_lo = L & 15, q = L >> 4;

    const float* src; int n, kb, Ksrc, dst16; float sc;
    if (g < 576) {
        const int m = g / 96, lf = g % 96;
        const float* hs[6] = {eWhh0, eWih1, eWhh1, dWhh0, dWih1, dWhh1};
        src = hs[m];
        const int nt = lf >> 2, kf = lf & 3;
        n = nt * 16 + n_lo; kb = kf * 32 + q * 8; Ksrc = 128;
        dst16 = m * 6144 + lf * 64 + L;
        sc = (n < 2 * HD) ? SC_RZ : SC_N;
    } else if (g < 600) {
        const int nt = g - 576;
        src = eWih0; n = nt * 16 + n_lo; kb = q * 8; Ksrc = 16;
        dst16 = OFF_EWIH0 + nt * 64 + L;
        sc = (n < 2 * HD) ? SC_RZ : SC_N;
    } else {
        const int lf = g - 600;
        src = fW1; n = (lf >> 2) * 16 + n_lo; kb = (lf & 3) * 32 + q * 8; Ksrc = 128;
        dst16 = OFF_FW1 + lf * 64 + L;
        sc = 1.f;
    }

    ushort_t h[8];
    #pragma unroll
    for (int j = 0; j < 8; ++j) {
        const int k = kb + j;
        h[j] = (k < Ksrc) ? f2bf(sc * src[n * Ksrc + k]) : (ushort_t)0;
    }
    uint4 o;
    o.x = (uint_t)h[0] | ((uint_t)h[1] << 16);
    o.y = (uint_t)h[2] | ((uint_t)h[3] << 16);
    o.z = (uint_t)h[4] | ((uint_t)h[5] << 16);
    o.w = (uint_t)h[6] | ((uint_t)h[7] << 16);
    ws[dst16] = o;
}

__device__ __forceinline__ void combineM(const f32x4& gr, const f32x4& gz,
                                         const f32x4& gn_i, const f32x4& gn_h,
                                         float* hreg, ushort_t* wb)
{
    #pragma unroll
    for (int r_ = 0; r_ < 4; ++r_) {
        const float rg = sig2(gr[r_]);
        const float zg = sig2(gz[r_]);
        const float ng = fmaf(2.f, sig2(gn_i[r_] + rg * gn_h[r_]), -1.f);
        const float hn = fmaf(zg, hreg[r_] - ng, ng);
        hreg[r_] = hn;
        wb[r_ * 8] = f2bf_h(hn);
    }
}

extern "C" __global__ __launch_bounds__(NT, 2)
void gru_seq2seq_kernel(
    const float* __restrict__ x,
    const float* __restrict__ ebih0, const float* __restrict__ ebhh0,
    const float* __restrict__ ebih1, const float* __restrict__ ebhh1,
    const float* __restrict__ dWih0, const float* __restrict__ dbih0,
    const float* __restrict__ dbhh0,
    const float* __restrict__ dbih1, const float* __restrict__ dbhh1,
    const float* __restrict__ fb1, const float* __restrict__ fW2,
    const float* __restrict__ fb2,
    const short8* __restrict__ wf,
    float* __restrict__ out)
{
    __shared__ ushort_t h0f[2][4][512];   // [buf][kf][lane*8+j]
    __shared__ ushort_t h1f[2][4][512];
    __shared__ ushort_t xf[2][512];
    __shared__ uint4 fw1l[1024];          // fW1 frags (decoder FC)

    const int t = threadIdx.x;
    const int L = t & 63, w = t >> 6;
    const int col16 = L & 15, q = L >> 4;
    const int col = w * 16 + col16;
    const int b0 = blockIdx.x * BT;

    for (int i = t; i < 4096; i += NT) {
        (&h0f[0][0][0])[i] = 0;
        (&h1f[0][0][0])[i] = 0;
    }
    for (int i = t; i < 1024; i += NT) (&xf[0][0])[i] = 0;

    const int kfc = col >> 5, qq = (col >> 3) & 3, jc = col & 7;
    const int hwo = kfc * 512 + (qq * 16 + q * 4) * 8 + jc;  // + r_*8 per row

    const int xr = t >> 4, xfeat = t & 15;
    const int xscat = (((xfeat >> 3) * 16) + (xr & 15)) * 8 + (xfeat & 7);
    float xv = (t < 256) ? x[((b0 + xr) * TIN + 0) * NFE + xfeat] : 0.f;

    // encoder per-lane bias scalars, PRE-SCALED
    const float e0_rz = SC_RZ * (ebih0[col] + ebhh0[col]);
    const float e0_zz = SC_RZ * (ebih0[HD + col] + ebhh0[HD + col]);
    const float e0_in = SC_N * ebih0[2 * HD + col];
    const float e0_hn = SC_N * ebhh0[2 * HD + col];
    const float e1_rz = SC_RZ * (ebih1[col] + ebhh1[col]);
    const float e1_zz = SC_RZ * (ebih1[HD + col] + ebhh1[HD + col]);
    const float e1_in = SC_N * ebih1[2 * HD + col];
    const float e1_hn = SC_N * ebhh1[2 * HD + col];

    float h0r[4] = {0, 0, 0, 0};
    float h1r[4] = {0, 0, 0, 0};

    // encoder weights -> registers
    short8 Wa[3][4], Wb[3][4], Wc[3][4];
    short8 We[3];
    #pragma unroll
    for (int t3 = 0; t3 < 3; ++t3) {
        const int nt = w + t3 * 8;
        We[t3] = wf[OFF_EWIH0 + nt * 64 + L];
        #pragma unroll
        for (int kf = 0; kf < 4; ++kf) {
            Wa[t3][kf] = wf[OFF_EWHH0 + (nt * 4 + kf) * 64 + L];
            Wb[t3][kf] = wf[OFF_EWIH1 + (nt * 4 + kf) * 64 + L];
            Wc[t3][kf] = wf[OFF_EWHH1 + (nt * 4 + kf) * 64 + L];
        }
    }

    barrier_lds();
    if (t < 256) {
        (&xf[0][0])[xscat] = f2bf_h(xv);                  // x(0)
        xv = x[((b0 + xr) * TIN + 1) * NFE + xfeat];
    }
    barrier_lds();

    // ---------------- encoder iter 0: L0 only ------------------------------
    {
        if (t < 256) {
            (&xf[0][0])[512 + xscat] = f2bf_h(xv);        // x(1) -> xf[1]
            xv = x[((b0 + xr) * TIN + 2) * NFE + xfeat];
        }
        const short8 Ax = *(const short8*)&xf[0][L * 8];
        short8 Ah[4];
        #pragma unroll
        for (int kf = 0; kf < 4; ++kf)
            Ah[kf] = *(const short8*)&h0f[0][kf][L * 8];
        f32x4 gr = splat4(e0_rz), gz = splat4(e0_zz);
        f32x4 gni = splat4(e0_in), gnh = splat4(e0_hn);
        #pragma unroll
        for (int kf = 0; kf < 4; ++kf) {
            gr  = __builtin_amdgcn_mfma_f32_16x16x32_bf16(Ah[kf], Wa[0][kf], gr,  0, 0, 0);
            gz  = __builtin_amdgcn_mfma_f32_16x16x32_bf16(Ah[kf], Wa[1][kf], gz,  0, 0, 0);
            gnh = __builtin_amdgcn_mfma_f32_16x16x32_bf16(Ah[kf], Wa[2][kf], gnh, 0, 0, 0);
        }
        gr  = __builtin_amdgcn_mfma_f32_16x16x32_bf16(Ax, We[0], gr,  0, 0, 0);
        gz  = __builtin_amdgcn_mfma_f32_16x16x32_bf16(Ax, We[1], gz,  0, 0, 0);
        gni = __builtin_amdgcn_mfma_f32_16x16x32_bf16(Ax, We[2], gni, 0, 0, 0);
        combineM(gr, gz, gni, gnh, h0r, &(&h0f[0][0][0])[2048 + hwo]);
        barrier_lds();
    }

    // ---------------- encoder main, x2-unrolled (compile-time parity P) -----
    // ENC_STEP(i, P): reads xf[P]/h0f[P]/h1f[P]; writes h0f[1-P]/h1f[1-P];
    // stages x(i+1) into xf[1-P]. Ordering: L0-MFMA, L1-MFMA, L0-combine
    // (overlaps L1 MFMA latency), L1-combine.
#define ENC_STEP(i, P)                                                         \
    {                                                                          \
        if (t < 256 && (i) + 1 < TIN) {                                        \
            (&xf[0][0])[(1 - (P)) * 512 + xscat] = f2bf_h(xv);                 \
            if ((i) + 2 < TIN) xv = x[((b0 + xr) * TIN + (i) + 2) * NFE + xfeat]; \
        }                                                                      \
        const short8 Ax = *(const short8*)&xf[P][L * 8];                       \
        short8 Ah0[4], Ah1[4];                                                 \
        _Pragma("unroll")                                                      \
        for (int kf = 0; kf < 4; ++kf) {                                       \
            Ah0[kf] = *(const short8*)&h0f[P][kf][L * 8];                      \
            Ah1[kf] = *(const short8*)&h1f[P][kf][L * 8];                      \
        }                                                                      \
        f32x4 a_r = splat4(e0_rz), a_z = splat4(e0_zz);                        \
        f32x4 a_ni = splat4(e0_in), a_nh = splat4(e0_hn);                      \
        _Pragma("unroll")                                                      \
        for (int kf = 0; kf < 4; ++kf) {                                       \
            a_r  = __builtin_amdgcn_mfma_f32_16x16x32_bf16(Ah0[kf], Wa[0][kf], a_r,  0, 0, 0); \
            a_z  = __builtin_amdgcn_mfma_f32_16x16x32_bf16(Ah0[kf], Wa[1][kf], a_z,  0, 0, 0); \
            a_nh = __builtin_amdgcn_mfma_f32_16x16x32_bf16(Ah0[kf], Wa[2][kf], a_nh, 0, 0, 0); \
        }                                                                      \
        a_r  = __builtin_amdgcn_mfma_f32_16x16x32_bf16(Ax, We[0], a_r,  0, 0, 0); \
        a_z  = __builtin_amdgcn_mfma_f32_16x16x32_bf16(Ax, We[1], a_z,  0, 0, 0); \
        a_ni = __builtin_amdgcn_mfma_f32_16x16x32_bf16(Ax, We[2], a_ni, 0, 0, 0); \
        f32x4 b_r = splat4(e1_rz), b_z = splat4(e1_zz);                        \
        f32x4 b_ni = splat4(e1_in), b_nh = splat4(e1_hn);                      \
        _Pragma("unroll")                                                      \
        for (int kf = 0; kf < 4; ++kf) {                                       \
            b_r  = __builtin_amdgcn_mfma_f32_16x16x32_bf16(Ah0[kf], Wb[0][kf], b_r,  0, 0, 0); \
            b_z  = __builtin_amdgcn_mfma_f32_16x16x32_bf16(Ah0[kf], Wb[1][kf], b_z,  0, 0, 0); \
            b_ni = __builtin_amdgcn_mfma_f32_16x16x32_bf16(Ah0[kf], Wb[2][kf], b_ni, 0, 0, 0); \
            b_r  = __builtin_amdgcn_mfma_f32_16x16x32_bf16(Ah1[kf], Wc[0][kf], b_r,  0, 0, 0); \
            b_z  = __builtin_amdgcn_mfma_f32_16x16x32_bf16(Ah1[kf], Wc[1][kf], b_z,  0, 0, 0); \
            b_nh = __builtin_amdgcn_mfma_f32_16x16x32_bf16(Ah1[kf], Wc[2][kf], b_nh, 0, 0, 0); \
        }                                                                      \
        combineM(a_r, a_z, a_ni, a_nh, h0r, &(&h0f[0][0][0])[(1 - (P)) * 2048 + hwo]); \
        combineM(b_r, b_z, b_ni, b_nh, h1r, &(&h1f[0][0][0])[(1 - (P)) * 2048 + hwo]); \
        barrier_lds();                                                         \
    }

    for (int i = 1; i + 1 < TIN; i += 2) {
        ENC_STEP(i, 1);
        ENC_STEP(i + 1, 0);
    }
    ENC_STEP(TIN - 1, 1);   // i=335 -> h0(335) in h0f[0], h1(334) in h1f[0]
#undef ENC_STEP

    // epilogue: L1(335)
    {
        short8 Ai[4], Ah[4];
        #pragma unroll
        for (int kf = 0; kf < 4; ++kf) {
            Ai[kf] = *(const short8*)&h0f[0][kf][L * 8];
            Ah[kf] = *(const short8*)&h1f[0][kf][L * 8];
        }
        f32x4 gr = splat4(e1_rz), gz = splat4(e1_zz);
        f32x4 gni = splat4(e1_in), gnh = splat4(e1_hn);
        #pragma unroll
        for (int kf = 0; kf < 4; ++kf) {
            gr  = __builtin_amdgcn_mfma_f32_16x16x32_bf16(Ai[kf], Wb[0][kf], gr,  0, 0, 0);
            gz  = __builtin_amdgcn_mfma_f32_16x16x32_bf16(Ai[kf], Wb[1][kf], gz,  0, 0, 0);
            gni = __builtin_amdgcn_mfma_f32_16x16x32_bf16(Ai[kf], Wb[2][kf], gni, 0, 0, 0);
            gr  = __builtin_amdgcn_mfma_f32_16x16x32_bf16(Ah[kf], Wc[0][kf], gr,  0, 0, 0);
            gz  = __builtin_amdgcn_mfma_f32_16x16x32_bf16(Ah[kf], Wc[1][kf], gz,  0, 0, 0);
            gnh = __builtin_amdgcn_mfma_f32_16x16x32_bf16(Ah[kf], Wc[2][kf], gnh, 0, 0, 0);
        }
        combineM(gr, gz, gni, gnh, h1r, &(&h1f[0][0][0])[2048 + hwo]);  // h1(-1) -> h1f[1]
        barrier_lds();
    }

    asm volatile("" ::: "memory");

    // ---- decoder prologue ----
    #pragma unroll
    for (int t3 = 0; t3 < 3; ++t3) {
        const int nt = w + t3 * 8;
        #pragma unroll
        for (int kf = 0; kf < 4; ++kf) {
            Wa[t3][kf] = wf[OFF_DWHH0 + (nt * 4 + kf) * 64 + L];
            Wb[t3][kf] = wf[OFF_DWIH1 + (nt * 4 + kf) * 64 + L];
            Wc[t3][kf] = wf[OFF_DWHH1 + (nt * 4 + kf) * 64 + L];
        }
    }
    for (int i = t; i < 1024; i += NT) fw1l[i] = ((const uint4*)wf)[OFF_FW1 + i];

    const float d0_rz = SC_RZ * (dbih0[col] + dbhh0[col]);
    const float d0_zz = SC_RZ * (dbih0[HD + col] + dbhh0[HD + col]);
    const float d0_in = SC_N * dbih0[2 * HD + col];
    const float d0_hn = SC_N * dbhh0[2 * HD + col];
    const float d1_rz = SC_RZ * (dbih1[col] + dbhh1[col]);
    const float d1_zz = SC_RZ * (dbih1[HD + col] + dbhh1[HD + col]);
    const float d1_in = SC_N * dbih1[2 * HD + col];
    const float d1_hn = SC_N * dbhh1[2 * HD + col];
    const float w0r = SC_RZ * dWih0[col];
    const float w0z = SC_RZ * dWih0[HD + col];
    const float w0n = SC_N * dWih0[2 * HD + col];
    float f1bv[4], w2v[4];
    #pragma unroll
    for (int nt = 0; nt < 4; ++nt) {
        f1bv[nt] = fb1[nt * 16 + col16];
        w2v[nt]  = fW2[nt * 16 + col16];
    }
    const float fb2v = fb2[0];
    float ivr[4] = {0.f, 0.f, 0.f, 0.f};

    // prologue: ghA from h0_enc, then combine h0(0) (inp(-1)=0) -> h0f[0]
    {
        short8 Ah[4];
        #pragma unroll
        for (int kf = 0; kf < 4; ++kf)
            Ah[kf] = *(const short8*)&h0f[0][kf][L * 8];
        f32x4 g0 = splat4(d0_rz), g1 = splat4(d0_zz), g2 = splat4(d0_hn);
        #pragma unroll
        for (int kf = 0; kf < 4; ++kf) {
            g0 = __builtin_amdgcn_mfma_f32_16x16x32_bf16(Ah[kf], Wa[0][kf], g0, 0, 0, 0);
            g1 = __builtin_amdgcn_mfma_f32_16x16x32_bf16(Ah[kf], Wa[1][kf], g1, 0, 0, 0);
            g2 = __builtin_amdgcn_mfma_f32_16x16x32_bf16(Ah[kf], Wa[2][kf], g2, 0, 0, 0);
        }
        barrier_lds();   // everyone done reading h0f[0] before overwrite
        ushort_t* wb = &(&h0f[0][0][0])[0 + hwo];
        #pragma unroll
        for (int r_ = 0; r_ < 4; ++r_) {
            const float rg = sig2(g0[r_]);
            const float zg = sig2(g1[r_]);
            const float ng = fmaf(2.f, sig2(d0_in + rg * g2[r_]), -1.f);
            const float hn = fmaf(zg, h0r[r_] - ng, ng);
            h0r[r_] = hn;
            wb[r_ * 8] = f2bf_h(hn);
        }
    }
    barrier_lds();

    // ---------------- decoder, x2-unrolled (compile-time parity P) ----------
    // h0(s) in h0f[P]; h1(s) in h1f[P] (h1(-1) in h1f[1]).
#define DEC_P2(P)                                                              \
    {                                                                          \
        short8 Ai[4], Ah[4];                                                   \
        _Pragma("unroll")                                                      \
        for (int kf = 0; kf < 4; ++kf) {                                       \
            Ai[kf] = *(const short8*)&h0f[P][kf][L * 8];                       \
            Ah[kf] = *(const short8*)&h1f[1 - (P)][kf][L * 8];                 \
        }                                                                      \
        f32x4 gr = splat4(d1_rz), gz = splat4(d1_zz);                          \
        f32x4 gni = splat4(d1_in), gnh = splat4(d1_hn);                        \
        _Pragma("unroll")                                                      \
        for (int kf = 0; kf < 4; ++kf) {                                       \
            gr  = __builtin_amdgcn_mfma_f32_16x16x32_bf16(Ai[kf], Wb[0][kf], gr,  0, 0, 0); \
            gz  = __builtin_amdgcn_mfma_f32_16x16x32_bf16(Ai[kf], Wb[1][kf], gz,  0, 0, 0); \
            gni = __builtin_amdgcn_mfma_f32_16x16x32_bf16(Ai[kf], Wb[2][kf], gni, 0, 0, 0); \
            gr  = __builtin_amdgcn_mfma_f32_16x16x32_bf16(Ah[kf], Wc[0][kf], gr,  0, 0, 0); \
            gz  = __builtin_amdgcn_mfma_f32_16x16x32_bf16(Ah[kf], Wc[1][kf], gz,  0, 0, 0); \
            gnh = __builtin_amdgcn_mfma_f32_16x16x32_bf16(Ah[kf], Wc[2][kf], gnh, 0, 0, 0); \
        }                                                                      \
        combineM(gr, gz, gni, gnh, h1r, &(&h1f[0][0][0])[(P) * 2048 + hwo]);   \
        barrier_lds();                                                         \
    }

#define DEC_P1(P, s)                                                           \
    {                                                                          \
        short8 Af[4], Ah[4];                                                   \
        _Pragma("unroll")                                                      \
        for (int kf = 0; kf < 4; ++kf) {                                       \
            Af[kf] = *(const short8*)&h1f[P][kf][L * 8];                       \
            Ah[kf] = *(const short8*)&h0f[P][kf][L * 8];                       \
        }                                                                      \
        f32x4 g0 = splat4(d0_rz), g1 = splat4(d0_zz), g2 = splat4(d0_hn);      \
        _Pragma("unroll")                                                      \
        for (int kf = 0; kf < 4; ++kf) {                                       \
            g0 = __builtin_amdgcn_mfma_f32_16x16x32_bf16(Ah[kf], Wa[0][kf], g0, 0, 0, 0); \
            g1 = __builtin_amdgcn_mfma_f32_16x16x32_bf16(Ah[kf], Wa[1][kf], g1, 0, 0, 0); \
            g2 = __builtin_amdgcn_mfma_f32_16x16x32_bf16(Ah[kf], Wa[2][kf], g2, 0, 0, 0); \
        }                                                                      \
        f32x4 fc[4];                                                           \
        _Pragma("unroll")                                                      \
        for (int nt = 0; nt < 4; ++nt) fc[nt] = splat4(0.f);                   \
        _Pragma("unroll")                                                      \
        for (int kf = 0; kf < 4; ++kf) {                                       \
            _Pragma("unroll")                                                  \
            for (int nt = 0; nt < 4; ++nt) {                                   \
                const short8 b = *(const short8*)&fw1l[(nt * 4 + kf) * 64 + L]; \
                fc[nt] = __builtin_amdgcn_mfma_f32_16x16x32_bf16(Af[kf], b, fc[nt], 0, 0, 0); \
            }                                                                  \
        }                                                                      \
        float ps[4];                                                           \
        _Pragma("unroll")                                                      \
        for (int r_ = 0; r_ < 4; ++r_) {                                       \
            float s_ = 0.f;                                                    \
            _Pragma("unroll")                                                  \
            for (int nt = 0; nt < 4; ++nt)                                     \
                s_ = fmaf(fmaxf(fc[nt][r_] + f1bv[nt], 0.f), w2v[nt], s_);     \
            ps[r_] = s_;                                                       \
        }                                                                      \
        _Pragma("unroll")                                                      \
        for (int r_ = 0; r_ < 4; ++r_) {                                       \
            ps[r_] += __shfl_xor(ps[r_], 1, 64);                               \
            ps[r_] += __shfl_xor(ps[r_], 2, 64);                               \
            ps[r_] += __shfl_xor(ps[r_], 4, 64);                               \
            ps[r_] += __shfl_xor(ps[r_], 8, 64);                               \
            ivr[r_] = fmaxf(ps[r_] + fb2v, 0.f);                               \
        }                                                                      \
        if (w == 0 && col16 == 0) {                                            \
            _Pragma("unroll")                                                  \
            for (int r_ = 0; r_ < 4; ++r_)                                     \
                out[(b0 + q * 4 + r_) * TOUT + (s)] = ivr[r_];                 \
        }                                                                      \
        if ((s) + 1 < TOUT) {                                                  \
            ushort_t* wb = &(&h0f[0][0][0])[(1 - (P)) * 2048 + hwo];           \
            _Pragma("unroll")                                                  \
            for (int r_ = 0; r_ < 4; ++r_) {                                   \
                const float iv = ivr[r_];                                      \
                const float rg = sig2(fmaf(iv, w0r, g0[r_]));                  \
                const float zg = sig2(fmaf(iv, w0z, g1[r_]));                  \
                const float tt = fmaf(iv, w0n, d0_in) + rg * g2[r_];           \
                const float ng = fmaf(2.f, sig2(tt), -1.f);                    \
                const float hn = fmaf(zg, h0r[r_] - ng, ng);                   \
                h0r[r_] = hn;                                                  \
                wb[r_ * 8] = f2bf_h(hn);                                       \
            }                                                                  \
        }                                                                      \
        barrier_lds();                                                         \
    }

    for (int s = 0; s < TOUT; s += 2) {
        DEC_P2(0);
        DEC_P1(0, s);
        DEC_P2(1);
        DEC_P1(1, s + 1);
    }
#undef DEC_P2
#undef DEC_P1
}

extern "C" void kernel_launch(void* const* d_in, const int* in_sizes, int n_in,
                              void* d_out, int out_size, void* d_ws, size_t ws_size,
                              hipStream_t stream) {
    const float* x     = (const float*)d_in[0];
    const float* eWih0 = (const float*)d_in[1];
    const float* eWhh0 = (const float*)d_in[2];
    const float* ebih0 = (const float*)d_in[3];
    const float* ebhh0 = (const float*)d_in[4];
    const float* eWih1 = (const float*)d_in[5];
    const float* eWhh1 = (const float*)d_in[6];
    const float* ebih1 = (const float*)d_in[7];
    const float* ebhh1 = (const float*)d_in[8];
    const float* dWih0 = (const float*)d_in[9];
    const float* dWhh0 = (const float*)d_in[10];
    const float* dbih0 = (const float*)d_in[11];
    const float* dbhh0 = (const float*)d_in[12];
    const float* dWih1 = (const float*)d_in[13];
    const float* dWhh1 = (const float*)d_in[14];
    const float* dbih1 = (const float*)d_in[15];
    const float* dbhh1 = (const float*)d_in[16];
    const float* fW1   = (const float*)d_in[17];
    const float* fb1   = (const float*)d_in[18];
    const float* fW2   = (const float*)d_in[19];
    const float* fb2   = (const float*)d_in[20];
    float* out = (float*)d_out;

    hipLaunchKernelGGL(prep_kernel, dim3(616), dim3(64), 0, stream,
                       eWhh0, eWih1, eWhh1, dWhh0, dWih1, dWhh1, eWih0, fW1,
                       (uint4*)d_ws);
    hipLaunchKernelGGL(gru_seq2seq_kernel, dim3(NB), dim3(NT), 0, stream,
                       x, ebih0, ebhh0, ebih1, ebhh1,
                       dWih0, dbih0, dbhh0, dbih1, dbhh1,
                       fb1, fW2, fb2,
                       (const short8*)d_ws, out);
}

// Round 10
// 814.500 us; speedup vs baseline: 1.0235x; 1.0235x over previous
//
#include <hip/hip_runtime.h>

// GRU seq2seq, MI355X gfx950. Round 10: revert to R8 structure (best: 818 us)
//   + keep only the cheap round-half-up h-store from R9.
//   Structure (pinned by HW): 128 blocks x 512 thr, 1 block/CU, 2 waves/SIMD
//   (weight regs 312/512 per SIMD), wave w owns gate cols [w*16,+16), weights
//   register/AGPR-resident, 1-barrier encoder phase with all 10 acc chains
//   interleaved in one kf loop (max ILP), 2-phase decoder.
//   Phase count 337+336 is minimal (cross-wave h exchange + FC feedback).

typedef unsigned short ushort_t;
typedef unsigned int uint_t;
typedef __attribute__((ext_vector_type(8))) short short8;
typedef __attribute__((ext_vector_type(4))) float f32x4;

#define BT   16
#define NT   512
#define HD   128
#define TIN  336
#define TOUT 168
#define NFE  16
#define NB   128

#define SC_RZ (-1.44269504089f)   // -log2(e)
#define SC_N  (-2.88539008177f)   // -2*log2(e)

#define OFF_EWHH0 0
#define OFF_EWIH1 6144
#define OFF_EWHH1 12288
#define OFF_DWHH0 18432
#define OFF_DWIH1 24576
#define OFF_DWHH1 30720
#define OFF_EWIH0 36864
#define OFF_FW1   38400

__device__ __forceinline__ ushort_t f2bf(float f) {      // RNE (prep only)
    union { float f; uint_t u; } v; v.f = f;
    uint_t r = v.u + 0x7FFFu + ((v.u >> 16) & 1u);
    return (ushort_t)(r >> 16);
}
__device__ __forceinline__ ushort_t f2bf_h(float f) {    // round-half-up, 2 VALU
    union { float f; uint_t u; } v; v.f = f;
    return (ushort_t)((v.u + 0x8000u) >> 16);
}
__device__ __forceinline__ f32x4 splat4(float v) {
    return (f32x4){v, v, v, v};
}
__device__ __forceinline__ float sig2(float t) {         // sigmoid of pre-scaled acc
    return __builtin_amdgcn_rcpf(1.f + __builtin_amdgcn_exp2f(t));
}
__device__ __forceinline__ void barrier_lds() {
    asm volatile("s_waitcnt lgkmcnt(0)\n\ts_barrier" ::: "memory");
}

// ---------------- prep: fp32 weights -> bf16 MFMA B-fragments ----------------
// Gate matrices PRE-SCALED: rows [0,256) by -log2e, rows [256,384) by -2log2e.
extern "C" __global__ __launch_bounds__(64)
void prep_kernel(const float* __restrict__ eWhh0, const float* __restrict__ eWih1,
                 const float* __restrict__ eWhh1, const float* __restrict__ dWhh0,
                 const float* __restrict__ dWih1, const float* __restrict__ dWhh1,
                 const float* __restrict__ eWih0, const float* __restrict__ fW1,
                 uint4* __restrict__ ws)
{
    const int g = blockIdx.x;
    const int L = threadIdx.x;
    const int n_lo = L & 15, q = L >> 4;

    const float* src; int n, kb, Ksrc, dst16; float sc;
    if (g < 576) {
        const int m = g / 96, lf = g % 96;
        const float* hs[6] = {eWhh0, eWih1, eWhh1, dWhh0, dWih1, dWhh1};
        src = hs[m];
        const int nt = lf >> 2, kf = lf & 3;
        n = nt * 16 + n_lo; kb = kf * 32 + q * 8; Ksrc = 128;
        dst16 = m * 6144 + lf * 64 + L;
        sc = (n < 2 * HD) ? SC_RZ : SC_N;
    } else if (g < 600) {
        const int nt = g - 576;
        src = eWih0; n = nt * 16 + n_lo; kb = q * 8; Ksrc = 16;
        dst16 = OFF_EWIH0 + nt * 64 + L;
        sc = (n < 2 * HD) ? SC_RZ : SC_N;
    } else {
        const int lf = g - 600;
        src = fW1; n = (lf >> 2) * 16 + n_lo; kb = (lf & 3) * 32 + q * 8; Ksrc = 128;
        dst16 = OFF_FW1 + lf * 64 + L;
        sc = 1.f;
    }

    ushort_t h[8];
    #pragma unroll
    for (int j = 0; j < 8; ++j) {
        const int k = kb + j;
        h[j] = (k < Ksrc) ? f2bf(sc * src[n * Ksrc + k]) : (ushort_t)0;
    }
    uint4 o;
    o.x = (uint_t)h[0] | ((uint_t)h[1] << 16);
    o.y = (uint_t)h[2] | ((uint_t)h[3] << 16);
    o.z = (uint_t)h[4] | ((uint_t)h[5] << 16);
    o.w = (uint_t)h[6] | ((uint_t)h[7] << 16);
    ws[dst16] = o;
}

__device__ __forceinline__ void combineM(const f32x4& gr, const f32x4& gz,
                                         const f32x4& gn_i, const f32x4& gn_h,
                                         float* hreg, ushort_t* wb)
{
    #pragma unroll
    for (int r_ = 0; r_ < 4; ++r_) {
        const float rg = sig2(gr[r_]);
        const float zg = sig2(gz[r_]);
        const float ng = fmaf(2.f, sig2(gn_i[r_] + rg * gn_h[r_]), -1.f);
        const float hn = fmaf(zg, hreg[r_] - ng, ng);
        hreg[r_] = hn;
        wb[r_ * 8] = f2bf_h(hn);
    }
}

extern "C" __global__ __launch_bounds__(NT, 2)
void gru_seq2seq_kernel(
    const float* __restrict__ x,
    const float* __restrict__ ebih0, const float* __restrict__ ebhh0,
    const float* __restrict__ ebih1, const float* __restrict__ ebhh1,
    const float* __restrict__ dWih0, const float* __restrict__ dbih0,
    const float* __restrict__ dbhh0,
    const float* __restrict__ dbih1, const float* __restrict__ dbhh1,
    const float* __restrict__ fb1, const float* __restrict__ fW2,
    const float* __restrict__ fb2,
    const short8* __restrict__ wf,
    float* __restrict__ out)
{
    __shared__ ushort_t h0f[2][4][512];   // [buf][kf][lane*8+j]
    __shared__ ushort_t h1f[2][4][512];
    __shared__ ushort_t xf[2][512];
    __shared__ uint4 fw1l[1024];          // fW1 frags (decoder FC)

    const int t = threadIdx.x;
    const int L = t & 63, w = t >> 6;
    const int col16 = L & 15, q = L >> 4;
    const int col = w * 16 + col16;
    const int b0 = blockIdx.x * BT;

    for (int i = t; i < 4096; i += NT) {
        (&h0f[0][0][0])[i] = 0;
        (&h1f[0][0][0])[i] = 0;
    }
    for (int i = t; i < 1024; i += NT) (&xf[0][0])[i] = 0;

    const int kfc = col >> 5, qq = (col >> 3) & 3, jc = col & 7;
    const int hwo = kfc * 512 + (qq * 16 + q * 4) * 8 + jc;  // + r_*8 per row

    const int xr = t >> 4, xfeat = t & 15;
    const int xscat = (((xfeat >> 3) * 16) + (xr & 15)) * 8 + (xfeat & 7);
    float xv = (t < 256) ? x[((b0 + xr) * TIN + 0) * NFE + xfeat] : 0.f;

    // encoder per-lane bias scalars, PRE-SCALED
    const float e0_rz = SC_RZ * (ebih0[col] + ebhh0[col]);
    const float e0_zz = SC_RZ * (ebih0[HD + col] + ebhh0[HD + col]);
    const float e0_in = SC_N * ebih0[2 * HD + col];
    const float e0_hn = SC_N * ebhh0[2 * HD + col];
    const float e1_rz = SC_RZ * (ebih1[col] + ebhh1[col]);
    const float e1_zz = SC_RZ * (ebih1[HD + col] + ebhh1[HD + col]);
    const float e1_in = SC_N * ebih1[2 * HD + col];
    const float e1_hn = SC_N * ebhh1[2 * HD + col];

    float h0r[4] = {0, 0, 0, 0};
    float h1r[4] = {0, 0, 0, 0};

    // encoder weights -> registers
    short8 Wa[3][4], Wb[3][4], Wc[3][4];
    short8 We[3];
    #pragma unroll
    for (int t3 = 0; t3 < 3; ++t3) {
        const int nt = w + t3 * 8;
        We[t3] = wf[OFF_EWIH0 + nt * 64 + L];
        #pragma unroll
        for (int kf = 0; kf < 4; ++kf) {
            Wa[t3][kf] = wf[OFF_EWHH0 + (nt * 4 + kf) * 64 + L];
            Wb[t3][kf] = wf[OFF_EWIH1 + (nt * 4 + kf) * 64 + L];
            Wc[t3][kf] = wf[OFF_EWHH1 + (nt * 4 + kf) * 64 + L];
        }
    }

    barrier_lds();
    if (t < 256) {
        (&xf[0][0])[xscat] = f2bf_h(xv);                  // x(0)
        xv = x[((b0 + xr) * TIN + 1) * NFE + xfeat];
    }
    barrier_lds();

    // ---------------- encoder, pipelined: iter i = L0(i) + L1(i-1) ----------
    {
        if (t < 256) {
            (&xf[0][0])[512 + xscat] = f2bf_h(xv);        // x(1) -> xf[1]
            xv = x[((b0 + xr) * TIN + 2) * NFE + xfeat];
        }
        const short8 Ax = *(const short8*)&xf[0][L * 8];
        short8 Ah[4];
        #pragma unroll
        for (int kf = 0; kf < 4; ++kf)
            Ah[kf] = *(const short8*)&h0f[0][kf][L * 8];
        f32x4 gr = splat4(e0_rz), gz = splat4(e0_zz);
        f32x4 gni = splat4(e0_in), gnh = splat4(e0_hn);
        #pragma unroll
        for (int kf = 0; kf < 4; ++kf) {
            gr  = __builtin_amdgcn_mfma_f32_16x16x32_bf16(Ah[kf], Wa[0][kf], gr,  0, 0, 0);
            gz  = __builtin_amdgcn_mfma_f32_16x16x32_bf16(Ah[kf], Wa[1][kf], gz,  0, 0, 0);
            gnh = __builtin_amdgcn_mfma_f32_16x16x32_bf16(Ah[kf], Wa[2][kf], gnh, 0, 0, 0);
        }
        gr  = __builtin_amdgcn_mfma_f32_16x16x32_bf16(Ax, We[0], gr,  0, 0, 0);
        gz  = __builtin_amdgcn_mfma_f32_16x16x32_bf16(Ax, We[1], gz,  0, 0, 0);
        gni = __builtin_amdgcn_mfma_f32_16x16x32_bf16(Ax, We[2], gni, 0, 0, 0);
        combineM(gr, gz, gni, gnh, h0r, &(&h0f[0][0][0])[2048 + hwo]);
        barrier_lds();
    }

    for (int i = 1; i < TIN; ++i) {
        const int p = i & 1;
        if (t < 256 && i + 1 < TIN) {
            (&xf[0][0])[(1 - p) * 512 + xscat] = f2bf_h(xv);
            if (i + 2 < TIN) xv = x[((b0 + xr) * TIN + i + 2) * NFE + xfeat];
        }
        const short8 Ax = *(const short8*)&xf[p][L * 8];
        short8 Ah0[4], Ah1[4];
        #pragma unroll
        for (int kf = 0; kf < 4; ++kf) {
            Ah0[kf] = *(const short8*)&h0f[p][kf][L * 8];  // h0(i-1)
            Ah1[kf] = *(const short8*)&h1f[p][kf][L * 8];  // h1(i-2)
        }
        f32x4 a_r = splat4(e0_rz), a_z = splat4(e0_zz);
        f32x4 a_ni = splat4(e0_in), a_nh = splat4(e0_hn);
        f32x4 b_r = splat4(e1_rz), b_z = splat4(e1_zz);
        f32x4 b_ni = splat4(e1_in), b_nh = splat4(e1_hn);
        #pragma unroll
        for (int kf = 0; kf < 4; ++kf) {
            a_r  = __builtin_amdgcn_mfma_f32_16x16x32_bf16(Ah0[kf], Wa[0][kf], a_r,  0, 0, 0);
            a_z  = __builtin_amdgcn_mfma_f32_16x16x32_bf16(Ah0[kf], Wa[1][kf], a_z,  0, 0, 0);
            a_nh = __builtin_amdgcn_mfma_f32_16x16x32_bf16(Ah0[kf], Wa[2][kf], a_nh, 0, 0, 0);
            b_r  = __builtin_amdgcn_mfma_f32_16x16x32_bf16(Ah0[kf], Wb[0][kf], b_r,  0, 0, 0);
            b_z  = __builtin_amdgcn_mfma_f32_16x16x32_bf16(Ah0[kf], Wb[1][kf], b_z,  0, 0, 0);
            b_ni = __builtin_amdgcn_mfma_f32_16x16x32_bf16(Ah0[kf], Wb[2][kf], b_ni, 0, 0, 0);
            b_r  = __builtin_amdgcn_mfma_f32_16x16x32_bf16(Ah1[kf], Wc[0][kf], b_r,  0, 0, 0);
            b_z  = __builtin_amdgcn_mfma_f32_16x16x32_bf16(Ah1[kf], Wc[1][kf], b_z,  0, 0, 0);
            b_nh = __builtin_amdgcn_mfma_f32_16x16x32_bf16(Ah1[kf], Wc[2][kf], b_nh, 0, 0, 0);
        }
        a_r  = __builtin_amdgcn_mfma_f32_16x16x32_bf16(Ax, We[0], a_r,  0, 0, 0);
        a_z  = __builtin_amdgcn_mfma_f32_16x16x32_bf16(Ax, We[1], a_z,  0, 0, 0);
        a_ni = __builtin_amdgcn_mfma_f32_16x16x32_bf16(Ax, We[2], a_ni, 0, 0, 0);

        combineM(a_r, a_z, a_ni, a_nh, h0r, &(&h0f[0][0][0])[(1 - p) * 2048 + hwo]);
        combineM(b_r, b_z, b_ni, b_nh, h1r, &(&h1f[0][0][0])[(1 - p) * 2048 + hwo]);
        barrier_lds();
    }

    // epilogue: L1(335).  h0(335) in h0f[0], h1(334) in h1f[0].
    {
        short8 Ai[4], Ah[4];
        #pragma unroll
        for (int kf = 0; kf < 4; ++kf) {
            Ai[kf] = *(const short8*)&h0f[0][kf][L * 8];
            Ah[kf] = *(const short8*)&h1f[0][kf][L * 8];
        }
        f32x4 gr = splat4(e1_rz), gz = splat4(e1_zz);
        f32x4 gni = splat4(e1_in), gnh = splat4(e1_hn);
        #pragma unroll
        for (int kf = 0; kf < 4; ++kf) {
            gr  = __builtin_amdgcn_mfma_f32_16x16x32_bf16(Ai[kf], Wb[0][kf], gr,  0, 0, 0);
            gz  = __builtin_amdgcn_mfma_f32_16x16x32_bf16(Ai[kf], Wb[1][kf], gz,  0, 0, 0);
            gni = __builtin_amdgcn_mfma_f32_16x16x32_bf16(Ai[kf], Wb[2][kf], gni, 0, 0, 0);
            gr  = __builtin_amdgcn_mfma_f32_16x16x32_bf16(Ah[kf], Wc[0][kf], gr,  0, 0, 0);
            gz  = __builtin_amdgcn_mfma_f32_16x16x32_bf16(Ah[kf], Wc[1][kf], gz,  0, 0, 0);
            gnh = __builtin_amdgcn_mfma_f32_16x16x32_bf16(Ah[kf], Wc[2][kf], gnh, 0, 0, 0);
        }
        combineM(gr, gz, gni, gnh, h1r, &(&h1f[0][0][0])[2048 + hwo]);  // h1(-1) -> h1f[1]
        barrier_lds();
    }

    asm volatile("" ::: "memory");

    // ---- decoder prologue: weights, fW1->LDS, biases, ghA(0), h0(0) --------
    #pragma unroll
    for (int t3 = 0; t3 < 3; ++t3) {
        const int nt = w + t3 * 8;
        #pragma unroll
        for (int kf = 0; kf < 4; ++kf) {
            Wa[t3][kf] = wf[OFF_DWHH0 + (nt * 4 + kf) * 64 + L];
            Wb[t3][kf] = wf[OFF_DWIH1 + (nt * 4 + kf) * 64 + L];
            Wc[t3][kf] = wf[OFF_DWHH1 + (nt * 4 + kf) * 64 + L];
        }
    }
    for (int i = t; i < 1024; i += NT) fw1l[i] = ((const uint4*)wf)[OFF_FW1 + i];

    const float d0_rz = SC_RZ * (dbih0[col] + dbhh0[col]);
    const float d0_zz = SC_RZ * (dbih0[HD + col] + dbhh0[HD + col]);
    const float d0_in = SC_N * dbih0[2 * HD + col];
    const float d0_hn = SC_N * dbhh0[2 * HD + col];
    const float d1_rz = SC_RZ * (dbih1[col] + dbhh1[col]);
    const float d1_zz = SC_RZ * (dbih1[HD + col] + dbhh1[HD + col]);
    const float d1_in = SC_N * dbih1[2 * HD + col];
    const float d1_hn = SC_N * dbhh1[2 * HD + col];
    const float w0r = SC_RZ * dWih0[col];
    const float w0z = SC_RZ * dWih0[HD + col];
    const float w0n = SC_N * dWih0[2 * HD + col];
    float f1bv[4], w2v[4];
    #pragma unroll
    for (int nt = 0; nt < 4; ++nt) {
        f1bv[nt] = fb1[nt * 16 + col16];
        w2v[nt]  = fW2[nt * 16 + col16];
    }
    const float fb2v = fb2[0];
    float ivr[4] = {0.f, 0.f, 0.f, 0.f};

    // prologue: ghA from h0_enc, then combine h0(0) (inp(-1)=0) -> h0f[0]
    {
        short8 Ah[4];
        #pragma unroll
        for (int kf = 0; kf < 4; ++kf)
            Ah[kf] = *(const short8*)&h0f[0][kf][L * 8];
        f32x4 g0 = splat4(d0_rz), g1 = splat4(d0_zz), g2 = splat4(d0_hn);
        #pragma unroll
        for (int kf = 0; kf < 4; ++kf) {
            g0 = __builtin_amdgcn_mfma_f32_16x16x32_bf16(Ah[kf], Wa[0][kf], g0, 0, 0, 0);
            g1 = __builtin_amdgcn_mfma_f32_16x16x32_bf16(Ah[kf], Wa[1][kf], g1, 0, 0, 0);
            g2 = __builtin_amdgcn_mfma_f32_16x16x32_bf16(Ah[kf], Wa[2][kf], g2, 0, 0, 0);
        }
        barrier_lds();   // everyone done reading h0f[0] before overwrite
        ushort_t* wb = &(&h0f[0][0][0])[0 + hwo];
        #pragma unroll
        for (int r_ = 0; r_ < 4; ++r_) {
            const float rg = sig2(g0[r_]);
            const float zg = sig2(g1[r_]);
            const float ng = fmaf(2.f, sig2(d0_in + rg * g2[r_]), -1.f);
            const float hn = fmaf(zg, h0r[r_] - ng, ng);
            h0r[r_] = hn;
            wb[r_ * 8] = f2bf_h(hn);
        }
    }
    barrier_lds();

    // ---------------- decoder: 2 balanced phases/step ----------------------
    // h0(s) in h0f[s&1]; h1(s) in h1f[s&1] (h1(-1) in h1f[1]).
    for (int s = 0; s < TOUT; ++s) {
        const int p = s & 1;

        // ----- P2(s): L1(s) only (24 MFMA) ---------------------------------
        {
            short8 Ai[4], Ah[4];
            #pragma unroll
            for (int kf = 0; kf < 4; ++kf) {
                Ai[kf] = *(const short8*)&h0f[p][kf][L * 8];      // h0(s)
                Ah[kf] = *(const short8*)&h1f[1 - p][kf][L * 8];  // h1(s-1)
            }
            f32x4 gr = splat4(d1_rz), gz = splat4(d1_zz);
            f32x4 gni = splat4(d1_in), gnh = splat4(d1_hn);
            #pragma unroll
            for (int kf = 0; kf < 4; ++kf) {
                gr  = __builtin_amdgcn_mfma_f32_16x16x32_bf16(Ai[kf], Wb[0][kf], gr,  0, 0, 0);
                gz  = __builtin_amdgcn_mfma_f32_16x16x32_bf16(Ai[kf], Wb[1][kf], gz,  0, 0, 0);
                gni = __builtin_amdgcn_mfma_f32_16x16x32_bf16(Ai[kf], Wb[2][kf], gni, 0, 0, 0);
                gr  = __builtin_amdgcn_mfma_f32_16x16x32_bf16(Ah[kf], Wc[0][kf], gr,  0, 0, 0);
                gz  = __builtin_amdgcn_mfma_f32_16x16x32_bf16(Ah[kf], Wc[1][kf], gz,  0, 0, 0);
                gnh = __builtin_amdgcn_mfma_f32_16x16x32_bf16(Ah[kf], Wc[2][kf], gnh, 0, 0, 0);
            }
            combineM(gr, gz, gni, gnh, h1r, &(&h1f[0][0][0])[p * 2048 + hwo]);  // h1(s)
        }
        barrier_lds();

        // ----- P1: FC(s) + ghA(s+1) + combine h0(s+1) (16+12 MFMA) ---------
        {
            short8 Af[4], Ah[4];
            #pragma unroll
            for (int kf = 0; kf < 4; ++kf) {
                Af[kf] = *(const short8*)&h1f[p][kf][L * 8];      // h1(s)
                Ah[kf] = *(const short8*)&h0f[p][kf][L * 8];      // h0(s)
            }
            // ghA(s+1) = dWhh0 . h0(s), bias-init (consumed below, in-phase)
            f32x4 g0 = splat4(d0_rz), g1 = splat4(d0_zz), g2 = splat4(d0_hn);
            f32x4 fc[4];
            #pragma unroll
            for (int nt = 0; nt < 4; ++nt) fc[nt] = splat4(0.f);
            #pragma unroll
            for (int kf = 0; kf < 4; ++kf) {
                g0 = __builtin_amdgcn_mfma_f32_16x16x32_bf16(Ah[kf], Wa[0][kf], g0, 0, 0, 0);
                g1 = __builtin_amdgcn_mfma_f32_16x16x32_bf16(Ah[kf], Wa[1][kf], g1, 0, 0, 0);
                g2 = __builtin_amdgcn_mfma_f32_16x16x32_bf16(Ah[kf], Wa[2][kf], g2, 0, 0, 0);
                #pragma unroll
                for (int nt = 0; nt < 4; ++nt) {
                    const short8 b = *(const short8*)&fw1l[(nt * 4 + kf) * 64 + L];
                    fc[nt] = __builtin_amdgcn_mfma_f32_16x16x32_bf16(Af[kf], b, fc[nt], 0, 0, 0);
                }
            }
            float ps[4];
            #pragma unroll
            for (int r_ = 0; r_ < 4; ++r_) {
                float s_ = 0.f;
                #pragma unroll
                for (int nt = 0; nt < 4; ++nt)
                    s_ = fmaf(fmaxf(fc[nt][r_] + f1bv[nt], 0.f), w2v[nt], s_);
                ps[r_] = s_;
            }
            #pragma unroll
            for (int r_ = 0; r_ < 4; ++r_) {
                ps[r_] += __shfl_xor(ps[r_], 1, 64);
                ps[r_] += __shfl_xor(ps[r_], 2, 64);
                ps[r_] += __shfl_xor(ps[r_], 4, 64);
                ps[r_] += __shfl_xor(ps[r_], 8, 64);
                ivr[r_] = fmaxf(ps[r_] + fb2v, 0.f);
            }
            if (w == 0 && col16 == 0) {
                #pragma unroll
                for (int r_ = 0; r_ < 4; ++r_)
                    out[(b0 + q * 4 + r_) * TOUT + s] = ivr[r_];
            }
            // combine h0(s+1) -> h0f[1-p]
            ushort_t* wb = &(&h0f[0][0][0])[(1 - p) * 2048 + hwo];
            #pragma unroll
            for (int r_ = 0; r_ < 4; ++r_) {
                const float iv = ivr[r_];
                const float rg = sig2(fmaf(iv, w0r, g0[r_]));
                const float zg = sig2(fmaf(iv, w0z, g1[r_]));
                const float tt = fmaf(iv, w0n, d0_in) + rg * g2[r_];
                const float ng = fmaf(2.f, sig2(tt), -1.f);
                const float hn = fmaf(zg, h0r[r_] - ng, ng);
                h0r[r_] = hn;
                wb[r_ * 8] = f2bf_h(hn);
            }
        }
        barrier_lds();
    }
}

extern "C" void kernel_launch(void* const* d_in, const int* in_sizes, int n_in,
                              void* d_out, int out_size, void* d_ws, size_t ws_size,
                              hipStream_t stream) {
    const float* x     = (const float*)d_in[0];
    const float* eWih0 = (const float*)d_in[1];
    const float* eWhh0 = (const float*)d_in[2];
    const float* ebih0 = (const float*)d_in[3];
    const float* ebhh0 = (const float*)d_in[4];
    const float* eWih1 = (const float*)d_in[5];
    const float* eWhh1 = (const float*)d_in[6];
    const float* ebih1 = (const float*)d_in[7];
    const float* ebhh1 = (const float*)d_in[8];
    const float* dWih0 = (const float*)d_in[9];
    const float* dWhh0 = (const float*)d_in[10];
    const float* dbih0 = (const float*)d_in[11];
    const float* dbhh0 = (const float*)d_in[12];
    const float* dWih1 = (const float*)d_in[13];
    const float* dWhh1 = (const float*)d_in[14];
    const float* dbih1 = (const float*)d_in[15];
    const float* dbhh1 = (const float*)d_in[16];
    const float* fW1   = (const float*)d_in[17];
    const float* fb1   = (const float*)d_in[18];
    const float* fW2   = (const float*)d_in[19];
    const float* fb2   = (const float*)d_in[20];
    float* out = (float*)d_out;

    hipLaunchKernelGGL(prep_kernel, dim3(616), dim3(64), 0, stream,
                       eWhh0, eWih1, eWhh1, dWhh0, dWih1, dWhh1, eWih0, fW1,
                       (uint4*)d_ws);
    hipLaunchKernelGGL(gru_seq2seq_kernel, dim3(NB), dim3(NT), 0, stream,
                       x, ebih0, ebhh0, ebih1, ebhh1,
                       dWih0, dbih0, dbhh0, dbih1, dbhh1,
                       fb1, fW2, fb2,
                       (const short8*)d_ws, out);
}